// Round 1
// baseline (659.576 us; speedup 1.0000x reference)
//
#include <hip/hip_runtime.h>
#include <math.h>

#define B_ 8
#define N_ 1024
#define C_ 320
#define H_ 5
#define D_ 64
#define M_ (B_*N_)

struct Gauss {
  float u[H_][7];
  float alpha[H_];
};

// ---------------- LayerNorm: one wave per row ----------------
__global__ __launch_bounds__(64) void ln_kernel(const float* __restrict__ x,
    const float* __restrict__ gamma, const float* __restrict__ beta,
    float* __restrict__ xn) {
  int row = blockIdx.x;
  int lane = threadIdx.x;
  const float* xr = x + (long)row * C_;
  float vals[5];
  float s = 0.f, ss = 0.f;
#pragma unroll
  for (int j = 0; j < 5; ++j) {
    float vv = xr[lane + 64*j];
    vals[j] = vv; s += vv; ss += vv*vv;
  }
#pragma unroll
  for (int o = 32; o > 0; o >>= 1) {
    s  += __shfl_xor(s, o, 64);
    ss += __shfl_xor(ss, o, 64);
  }
  float mean = s * (1.0f/C_);
  float var  = ss * (1.0f/C_) - mean*mean;
  float rstd = rsqrtf(var + 1e-5f);
  float* outr = xn + (long)row * C_;
#pragma unroll
  for (int j = 0; j < 5; ++j) {
    int c = lane + 64*j;
    outr[c] = (vals[j]-mean)*rstd*gamma[c] + beta[c];
  }
}

// ---------------- QKV GEMM (8192x320 @ 320x960^T) + scatter ----------------
// out[m][col] = sum_k xn[m][k]*w[col][k] + bias[col]; scatter col=(3,H,d)
__global__ __launch_bounds__(256) void qkv_kernel(const float* __restrict__ xn,
    const float* __restrict__ w, const float* __restrict__ bias,
    float* __restrict__ q, float* __restrict__ k, float* __restrict__ v) {
  __shared__ float As[16][68];
  __shared__ float Bs[16][68];
  int j0 = blockIdx.x * 64;
  int m0 = blockIdx.y * 64;
  int tid = threadIdx.x;
  int tx = tid & 15, ty = tid >> 4;
  int lr = tid >> 2;
  int lc = (tid & 3) << 2;
  float acc[4][4] = {};
  for (int kk = 0; kk < C_; kk += 16) {
    float4 a4 = *(const float4*)(xn + (long)(m0+lr)*C_ + kk + lc);
    float4 b4 = *(const float4*)(w  + (long)(j0+lr)*C_ + kk + lc);
    As[lc+0][lr]=a4.x; As[lc+1][lr]=a4.y; As[lc+2][lr]=a4.z; As[lc+3][lr]=a4.w;
    Bs[lc+0][lr]=b4.x; Bs[lc+1][lr]=b4.y; Bs[lc+2][lr]=b4.z; Bs[lc+3][lr]=b4.w;
    __syncthreads();
#pragma unroll
    for (int p = 0; p < 16; ++p) {
      float4 av = *(const float4*)&As[p][ty<<2];
      float4 bv = *(const float4*)&Bs[p][tx<<2];
      float aa[4] = {av.x,av.y,av.z,av.w};
      float bb[4] = {bv.x,bv.y,bv.z,bv.w};
#pragma unroll
      for (int i=0;i<4;++i)
#pragma unroll
        for (int j=0;j<4;++j) acc[i][j] += aa[i]*bb[j];
    }
    __syncthreads();
  }
#pragma unroll
  for (int i=0;i<4;++i) {
    int m = m0 + (ty<<2) + i;
    int bb2 = m >> 10, n = m & (N_-1);
#pragma unroll
    for (int j=0;j<4;++j) {
      int col = j0 + (tx<<2) + j;
      float val = acc[i][j] + bias[col];
      int three = col / 320;
      int rem = col - three*320;
      int h = rem >> 6, dd = rem & 63;
      long idx = (((long)bb2*H_ + h)*N_ + n)*D_ + dd;
      if (three == 0)      q[idx] = val * 0.125f;   // fold d^-0.5
      else if (three == 1) k[idx] = val;
      else                 v[idx] = val;
    }
  }
}

// ---------------- QK^T per (b,h): 1024x1024 = q(1024x64) @ k^T ----------------
__global__ __launch_bounds__(256) void qk_kernel(const float* __restrict__ q,
    const float* __restrict__ kmat, float* __restrict__ attn) {
  __shared__ float Qs[64][68];
  __shared__ float Ks[64][68];
  int bh = blockIdx.z;
  int mm0 = blockIdx.x * 64;
  int n0 = blockIdx.y * 64;
  int tid = threadIdx.x;
  int tx = tid & 15, ty = tid >> 4;
  int lr = tid >> 2;
  const float* qb = q + (long)bh*N_*D_;
  const float* kb = kmat + (long)bh*N_*D_;
#pragma unroll
  for (int s = 0; s < 4; ++s) {
    int c = ((tid & 3) + (s<<2)) << 2;
    float4 a4 = *(const float4*)(qb + (long)(n0+lr)*D_ + c);
    float4 b4 = *(const float4*)(kb + (long)(mm0+lr)*D_ + c);
    Qs[c+0][lr]=a4.x; Qs[c+1][lr]=a4.y; Qs[c+2][lr]=a4.z; Qs[c+3][lr]=a4.w;
    Ks[c+0][lr]=b4.x; Ks[c+1][lr]=b4.y; Ks[c+2][lr]=b4.z; Ks[c+3][lr]=b4.w;
  }
  __syncthreads();
  float acc[4][4] = {};
#pragma unroll 8
  for (int p = 0; p < 64; ++p) {
    float4 av = *(const float4*)&Qs[p][ty<<2];
    float4 bv = *(const float4*)&Ks[p][tx<<2];
    float aa[4] = {av.x,av.y,av.z,av.w};
    float bb[4] = {bv.x,bv.y,bv.z,bv.w};
#pragma unroll
    for (int i=0;i<4;++i)
#pragma unroll
      for (int j=0;j<4;++j) acc[i][j] += aa[i]*bb[j];
  }
  float* ob = attn + ((long)bh*N_ + n0)*N_ + mm0;
#pragma unroll
  for (int i=0;i<4;++i) {
    float4 st = make_float4(acc[i][0],acc[i][1],acc[i][2],acc[i][3]);
    *(float4*)(ob + (long)((ty<<2)+i)*N_ + (tx<<2)) = st;
  }
}

// ------- Fused separable blur + softmax + PV: one block per (b,h, 8 rows) -------
#define TM 8
__global__ __launch_bounds__(256) void bsp_kernel(const float* __restrict__ attn,
    const float* __restrict__ v, float* __restrict__ ao, Gauss gw) {
  __shared__ float P[TM][N_];       // 32 KB: exp(combined) rows
  __shared__ float rowbuf[N_];      // col-blurred current row
  __shared__ float red[8];
  __shared__ float rowsum[TM];
  int bh = blockIdx.y;
  int h = bh % H_;
  int n0 = blockIdx.x * TM;
  int tid = threadIdx.x;
  const float* ab = attn + (long)bh*N_*N_;
  float u[7];
#pragma unroll
  for (int t=0;t<7;++t) u[t] = gw.u[h][t];
  float alpha = gw.alpha[h];

  for (int r = 0; r < TM; ++r) {
    int n = n0 + r;
    float center[4];
    // Phase A: column blur (over rows, reflect)
#pragma unroll
    for (int i = 0; i < 4; ++i) {
      int m = tid + (i<<8);
      float cb = 0.f;
#pragma unroll
      for (int dy = 0; dy < 7; ++dy) {
        int rr = n - 3 + dy;
        rr = rr < 0 ? -rr : (rr >= N_ ? 2*N_-2-rr : rr);
        float av = ab[(long)rr*N_ + m];
        if (dy == 3) center[i] = av;
        cb += u[dy]*av;
      }
      rowbuf[m] = cb;
    }
    __syncthreads();
    // Phase B: row blur (over cols, reflect) + combined + max
    float lmax = -1e30f;
    float pv[4];
#pragma unroll
    for (int i = 0; i < 4; ++i) {
      int m = tid + (i<<8);
      float rb = 0.f;
#pragma unroll
      for (int dx = 0; dx < 7; ++dx) {
        int mm = m - 3 + dx;
        mm = mm < 0 ? -mm : (mm >= N_ ? 2*N_-2-mm : mm);
        rb += u[dx]*rowbuf[mm];
      }
      float val = center[i] + alpha*rb;
      pv[i] = val;
      lmax = fmaxf(lmax, val);
    }
#pragma unroll
    for (int o=32;o>0;o>>=1) lmax = fmaxf(lmax, __shfl_xor(lmax,o,64));
    if ((tid & 63) == 0) red[tid>>6] = lmax;
    __syncthreads();
    float bmax = fmaxf(fmaxf(red[0],red[1]), fmaxf(red[2],red[3]));
    float lsum = 0.f;
#pragma unroll
    for (int i=0;i<4;++i) {
      float e = __expf(pv[i] - bmax);
      P[r][tid + (i<<8)] = e;
      lsum += e;
    }
#pragma unroll
    for (int o=32;o>0;o>>=1) lsum += __shfl_xor(lsum,o,64);
    if ((tid & 63) == 0) red[4 + (tid>>6)] = lsum;
    __syncthreads();
    if (tid == 0) rowsum[r] = red[4]+red[5]+red[6]+red[7];
    __syncthreads();  // also protects rowbuf reuse next iteration
  }
  // PV: (8 x 1024) @ (1024 x 64); thread = (col c, row-group g)
  int c = tid & 63, g = tid >> 6;
  const float* vb = v + (long)bh*N_*D_;
  float acc0 = 0.f, acc1 = 0.f;
#pragma unroll 4
  for (int m = 0; m < N_; ++m) {
    float vv = vb[m*D_ + c];
    acc0 += P[(g<<1)+0][m]*vv;   // LDS broadcast within wave
    acc1 += P[(g<<1)+1][m]*vv;
  }
  float* aob = ao + ((long)bh*N_ + n0)*D_ + c;
  aob[(long)((g<<1)+0)*D_] = acc0 / rowsum[(g<<1)+0];
  aob[(long)((g<<1)+1)*D_] = acc1 / rowsum[(g<<1)+1];
}

// ---------------- proj GEMM (8192x320 @ 320x320^T), gathered A ----------------
__global__ __launch_bounds__(256) void proj_kernel(const float* __restrict__ ao,
    const float* __restrict__ w, const float* __restrict__ bias,
    float* __restrict__ out) {
  __shared__ float As[16][68];
  __shared__ float Bs[16][68];
  int j0 = blockIdx.x * 64;
  int m0 = blockIdx.y * 64;
  int tid = threadIdx.x;
  int tx = tid & 15, ty = tid >> 4;
  int lr = tid >> 2;
  int lc = (tid & 3) << 2;
  int m = m0 + lr;
  int bb2 = m >> 10, n = m & (N_-1);
  float acc[4][4] = {};
  for (int kk = 0; kk < C_; kk += 16) {
    int kcol = kk + lc;
    int h = kcol >> 6, dd = kcol & 63;
    float4 a4 = *(const float4*)(ao + (((long)bb2*H_ + h)*N_ + n)*D_ + dd);
    float4 b4 = *(const float4*)(w + (long)(j0+lr)*C_ + kcol);
    As[lc+0][lr]=a4.x; As[lc+1][lr]=a4.y; As[lc+2][lr]=a4.z; As[lc+3][lr]=a4.w;
    Bs[lc+0][lr]=b4.x; Bs[lc+1][lr]=b4.y; Bs[lc+2][lr]=b4.z; Bs[lc+3][lr]=b4.w;
    __syncthreads();
#pragma unroll
    for (int p = 0; p < 16; ++p) {
      float4 av = *(const float4*)&As[p][ty<<2];
      float4 bv = *(const float4*)&Bs[p][tx<<2];
      float aa[4] = {av.x,av.y,av.z,av.w};
      float bb[4] = {bv.x,bv.y,bv.z,bv.w};
#pragma unroll
      for (int i=0;i<4;++i)
#pragma unroll
        for (int j=0;j<4;++j) acc[i][j] += aa[i]*bb[j];
    }
    __syncthreads();
  }
#pragma unroll
  for (int i=0;i<4;++i) {
    int mm = m0 + (ty<<2) + i;
    float* orow = out + (long)mm*C_ + j0 + (tx<<2);
    float4 bi = *(const float4*)(bias + j0 + (tx<<2));
    float4 st = make_float4(acc[i][0]+bi.x, acc[i][1]+bi.y,
                            acc[i][2]+bi.z, acc[i][3]+bi.w);
    *(float4*)orow = st;
  }
}

extern "C" void kernel_launch(void* const* d_in, const int* in_sizes, int n_in,
                              void* d_out, int out_size, void* d_ws, size_t ws_size,
                              hipStream_t stream) {
  const float* x      = (const float*)d_in[0];
  const float* ln_g   = (const float*)d_in[1];
  const float* ln_b   = (const float*)d_in[2];
  const float* qkv_w  = (const float*)d_in[3];
  const float* qkv_b  = (const float*)d_in[4];
  const float* proj_w = (const float*)d_in[5];
  const float* proj_b = (const float*)d_in[6];
  float* out = (float*)d_out;

  float* ws = (float*)d_ws;
  const long sz_bhnd = (long)B_*H_*N_*D_;   // 2,621,440
  float* xn   = ws;
  float* q    = xn  + (long)M_*C_;
  float* k    = q   + sz_bhnd;
  float* v    = k   + sz_bhnd;
  float* ao   = v   + sz_bhnd;
  float* attn = ao  + sz_bhnd;              // 41,943,040 floats

  // Host-side Gaussian 1D kernels (separable: K = outer(u,u), u = g/sum(g))
  Gauss gw;
  const float sig[H_] = {1.f, 2.f, 3.f, 4.f, 5.f};
  for (int h = 0; h < H_; ++h) {
    float g[7], s = 0.f;
    for (int t = 0; t < 7; ++t) {
      float xx = (float)(t - 3);
      g[t] = expf(-xx*xx / (2.f*sig[h]*sig[h]));
      s += g[t];
    }
    for (int t = 0; t < 7; ++t) gw.u[h][t] = g[t] / s;
    gw.alpha[h] = 0.1f * (float)(h+1);
  }

  ln_kernel<<<M_, 64, 0, stream>>>(x, ln_g, ln_b, xn);
  qkv_kernel<<<dim3(15, 128), 256, 0, stream>>>(xn, qkv_w, qkv_b, q, k, v);
  qk_kernel<<<dim3(16, 16, B_*H_), 256, 0, stream>>>(q, k, attn);
  bsp_kernel<<<dim3(N_/TM, B_*H_), 256, 0, stream>>>(attn, v, ao, gw);
  proj_kernel<<<dim3(5, 128), 256, 0, stream>>>(ao, proj_w, proj_b, out);
}

// Round 2
// 654.540 us; speedup vs baseline: 1.0077x; 1.0077x over previous
//
#include <hip/hip_runtime.h>
#include <math.h>

#define B_ 8
#define N_ 1024
#define C_ 320
#define H_ 5
#define D_ 64
#define M_ (B_*N_)
#define TM 16

typedef unsigned short ushort_t;
typedef __attribute__((ext_vector_type(8))) short bf16x8;
typedef __attribute__((ext_vector_type(4))) float f32x4;

struct Gauss {
  float u[H_][7];   // 1D gaussian (normalized)
  float au[H_][7];  // alpha * u
};

// fp32 -> bf16 RNE (manual, version-stable)
__device__ __forceinline__ ushort_t f2b(float f) {
  union { float f; unsigned u; } c; c.f = f;
  unsigned r = c.u + 0x7fffu + ((c.u >> 16) & 1u);
  return (ushort_t)(r >> 16);
}
__device__ __forceinline__ float b2f(ushort_t u) {
  union { float f; unsigned u; } c; c.u = ((unsigned)u) << 16;
  return c.f;
}

// ---------------- LayerNorm: one wave per row ----------------
__global__ __launch_bounds__(64) void ln_kernel(const float* __restrict__ x,
    const float* __restrict__ gamma, const float* __restrict__ beta,
    float* __restrict__ xn) {
  int row = blockIdx.x;
  int lane = threadIdx.x;
  const float* xr = x + (long)row * C_;
  float vals[5];
  float s = 0.f, ss = 0.f;
#pragma unroll
  for (int j = 0; j < 5; ++j) {
    float vv = xr[lane + 64*j];
    vals[j] = vv; s += vv; ss += vv*vv;
  }
#pragma unroll
  for (int o = 32; o > 0; o >>= 1) {
    s  += __shfl_xor(s, o, 64);
    ss += __shfl_xor(ss, o, 64);
  }
  float mean = s * (1.0f/C_);
  float var  = ss * (1.0f/C_) - mean*mean;
  float rstd = rsqrtf(var + 1e-5f);
  float* outr = xn + (long)row * C_;
#pragma unroll
  for (int j = 0; j < 5; ++j) {
    int c = lane + 64*j;
    outr[c] = (vals[j]-mean)*rstd*gamma[c] + beta[c];
  }
}

// ---------------- QKV GEMM (8192x320 @ 320x960^T) + scatter ----------------
// q,k fp32 in (B,H,N,d); v stored TRANSPOSED bf16: vt[bh][d][n]
__global__ __launch_bounds__(256) void qkv_kernel(const float* __restrict__ xn,
    const float* __restrict__ w, const float* __restrict__ bias,
    float* __restrict__ q, float* __restrict__ k, ushort_t* __restrict__ vt) {
  __shared__ float As[16][68];
  __shared__ float Bs[16][68];
  int j0 = blockIdx.x * 64;
  int m0 = blockIdx.y * 64;
  int tid = threadIdx.x;
  int tx = tid & 15, ty = tid >> 4;
  int lr = tid >> 2;
  int lc = (tid & 3) << 2;
  float acc[4][4] = {};
  for (int kk = 0; kk < C_; kk += 16) {
    float4 a4 = *(const float4*)(xn + (long)(m0+lr)*C_ + kk + lc);
    float4 b4 = *(const float4*)(w  + (long)(j0+lr)*C_ + kk + lc);
    As[lc+0][lr]=a4.x; As[lc+1][lr]=a4.y; As[lc+2][lr]=a4.z; As[lc+3][lr]=a4.w;
    Bs[lc+0][lr]=b4.x; Bs[lc+1][lr]=b4.y; Bs[lc+2][lr]=b4.z; Bs[lc+3][lr]=b4.w;
    __syncthreads();
#pragma unroll
    for (int p = 0; p < 16; ++p) {
      float4 av = *(const float4*)&As[p][ty<<2];
      float4 bv = *(const float4*)&Bs[p][tx<<2];
      float aa[4] = {av.x,av.y,av.z,av.w};
      float bb[4] = {bv.x,bv.y,bv.z,bv.w};
#pragma unroll
      for (int i=0;i<4;++i)
#pragma unroll
        for (int j=0;j<4;++j) acc[i][j] += aa[i]*bb[j];
    }
    __syncthreads();
  }
#pragma unroll
  for (int i=0;i<4;++i) {
    int m = m0 + (ty<<2) + i;
    int bb2 = m >> 10, n = m & (N_-1);
#pragma unroll
    for (int j=0;j<4;++j) {
      int col = j0 + (tx<<2) + j;
      float val = acc[i][j] + bias[col];
      int three = col / 320;
      int rem = col - three*320;
      int h = rem >> 6, dd = rem & 63;
      if (three == 0) {
        q[(((long)bb2*H_ + h)*N_ + n)*D_ + dd] = val * 0.125f;  // fold d^-0.5
      } else if (three == 1) {
        k[(((long)bb2*H_ + h)*N_ + n)*D_ + dd] = val;
      } else {
        vt[(((long)bb2*H_ + h)*D_ + dd)*N_ + n] = f2b(val);
      }
    }
  }
}

// ---------------- QK^T per (b,h): scores stored bf16 ----------------
__global__ __launch_bounds__(256) void qk_kernel(const float* __restrict__ q,
    const float* __restrict__ kmat, ushort_t* __restrict__ attn) {
  __shared__ float Qs[64][68];
  __shared__ float Ks[64][68];
  int bh = blockIdx.z;
  int mm0 = blockIdx.x * 64;
  int n0 = blockIdx.y * 64;
  int tid = threadIdx.x;
  int tx = tid & 15, ty = tid >> 4;
  int lr = tid >> 2;
  const float* qb = q + (long)bh*N_*D_;
  const float* kb = kmat + (long)bh*N_*D_;
#pragma unroll
  for (int s = 0; s < 4; ++s) {
    int c = ((tid & 3) + (s<<2)) << 2;
    float4 a4 = *(const float4*)(qb + (long)(n0+lr)*D_ + c);
    float4 b4 = *(const float4*)(kb + (long)(mm0+lr)*D_ + c);
    Qs[c+0][lr]=a4.x; Qs[c+1][lr]=a4.y; Qs[c+2][lr]=a4.z; Qs[c+3][lr]=a4.w;
    Ks[c+0][lr]=b4.x; Ks[c+1][lr]=b4.y; Ks[c+2][lr]=b4.z; Ks[c+3][lr]=b4.w;
  }
  __syncthreads();
  float acc[4][4] = {};
#pragma unroll 8
  for (int p = 0; p < 64; ++p) {
    float4 av = *(const float4*)&Qs[p][ty<<2];
    float4 bv = *(const float4*)&Ks[p][tx<<2];
    float aa[4] = {av.x,av.y,av.z,av.w};
    float bb[4] = {bv.x,bv.y,bv.z,bv.w};
#pragma unroll
    for (int i=0;i<4;++i)
#pragma unroll
      for (int j=0;j<4;++j) acc[i][j] += aa[i]*bb[j];
  }
  ushort_t* ob = attn + ((long)bh*N_ + n0)*N_ + mm0;
#pragma unroll
  for (int i=0;i<4;++i) {
    ushort_t st[4] = {f2b(acc[i][0]), f2b(acc[i][1]), f2b(acc[i][2]), f2b(acc[i][3])};
    *(uint2*)(ob + (long)((ty<<2)+i)*N_ + (tx<<2)) = *(const uint2*)st;
  }
}

// ------- Fused separable blur + softmax + MFMA PV -------
// Block: 1024 threads, TM=16 rows of one (b,h). Thread owns one column m.
__global__ __launch_bounds__(1024, 8) void bsp_kernel(
    const ushort_t* __restrict__ attn, const ushort_t* __restrict__ vt,
    float* __restrict__ ao, Gauss gw) {
  __shared__ ushort_t P[TM][1032];    // bf16 exp(logits), +8 pad (16B) for A-frag banking
  __shared__ float scratch[4096];     // rowbuf[1024] | wredmax[256]@1024 | wredsum[256]@1280 ; later PV partials [12][256]
  __shared__ float bmax[TM], bsum[TM];

  int bh = blockIdx.y;
  int h = bh % H_;
  int n0 = blockIdx.x * TM;
  int tid = threadIdx.x;
  int m = tid;
  int lane = tid & 63, wv = tid >> 6;
  const ushort_t* ab = attn + (long)bh*N_*N_;

  float u[7], au[7];
#pragma unroll
  for (int t = 0; t < 7; ++t) { u[t] = gw.u[h][t]; au[t] = gw.au[h][t]; }

  // column-neighbor indices with reflect (fixed for all rows)
  int nb[7];
#pragma unroll
  for (int dx = 0; dx < 7; ++dx) {
    int mm = m - 3 + dx;
    mm = mm < 0 ? -mm : (mm > N_-1 ? 2*N_-2-mm : mm);
    nb[dx] = mm;
  }

  float acc[TM];
#pragma unroll
  for (int r = 0; r < TM; ++r) acc[r] = 0.f;

  // stream 22 rows: p = n0-3 .. n0+18 (reflect), row-blur each, accumulate columns
  int p0 = n0 - 3;
  int rr0 = p0 < 0 ? -p0 : (p0 > N_-1 ? 2*N_-2-p0 : p0);
  float val = b2f(ab[(long)rr0*N_ + m]);
#pragma unroll
  for (int step = 0; step < TM + 6; ++step) {
    float vnext = 0.f;
    if (step < TM + 5) {
      int p = n0 - 2 + step;
      int rr = p < 0 ? -p : (p > N_-1 ? 2*N_-2-p : p);
      vnext = b2f(ab[(long)rr*N_ + m]);   // prefetch next row
    }
    scratch[m] = val;
    __syncthreads();
    float rb = 0.f;
#pragma unroll
    for (int dx = 0; dx < 7; ++dx) rb += u[dx] * scratch[nb[dx]];
    __syncthreads();
    // output rows receiving this source row: r in [step-6, step], dy = step-r
#pragma unroll
    for (int r = 0; r < TM; ++r) {
      if (r <= step && step <= r + 6) {
        acc[r] += au[step - r] * rb;       // alpha * blur
        if (step == r + 3) acc[r] += val;  // + raw center
      }
    }
    val = vnext;
  }

  // ---- softmax over m (block-wide, batched for 16 rows) ----
#pragma unroll
  for (int r = 0; r < TM; ++r) {
    float mx = acc[r];
#pragma unroll
    for (int o = 32; o > 0; o >>= 1) mx = fmaxf(mx, __shfl_xor(mx, o, 64));
    if (lane == 0) scratch[1024 + wv*16 + r] = mx;
  }
  __syncthreads();
  if (tid < 16) {
    float mx = -1e30f;
#pragma unroll
    for (int ww = 0; ww < 16; ++ww) mx = fmaxf(mx, scratch[1024 + ww*16 + tid]);
    bmax[tid] = mx;
  }
  __syncthreads();
#pragma unroll
  for (int r = 0; r < TM; ++r) {
    float e = __expf(acc[r] - bmax[r]);
    P[r][m] = f2b(e);
    acc[r] = e;
  }
#pragma unroll
  for (int r = 0; r < TM; ++r) {
    float sm = acc[r];
#pragma unroll
    for (int o = 32; o > 0; o >>= 1) sm += __shfl_xor(sm, o, 64);
    if (lane == 0) scratch[1280 + wv*16 + r] = sm;
  }
  __syncthreads();
  if (tid < 16) {
    float sm = 0.f;
#pragma unroll
    for (int ww = 0; ww < 16; ++ww) sm += scratch[1280 + ww*16 + tid];
    bsum[tid] = sm;
  }
  __syncthreads();   // P + bsum ready; scratch free for PV partials

  // ---- PV via MFMA: out[16][64] = P[16][1024] @ V[1024][64] ----
  // wave wv: dt = wv&3 (d-tile of 16), kc = wv>>2 (K-chunk of 256)
  int dt = wv & 3, kc = wv >> 2;
  int qd = lane >> 4, l16 = lane & 15;
  f32x4 pvacc = {0.f, 0.f, 0.f, 0.f};
  const ushort_t* vtb = vt + ((long)bh*D_ + dt*16 + l16)*N_;
#pragma unroll
  for (int s = 0; s < 8; ++s) {
    int k0 = kc*256 + s*32 + qd*8;
    bf16x8 afrag = *(const bf16x8*)&P[l16][k0];
    bf16x8 bfrag = *(const bf16x8*)(vtb + k0);
    pvacc = __builtin_amdgcn_mfma_f32_16x16x32_bf16(afrag, bfrag, pvacc, 0, 0, 0);
  }
  if (kc > 0) {
    *(f32x4*)(scratch + ((kc-1)*4 + dt)*256 + lane*4) = pvacc;
  }
  __syncthreads();
  if (kc == 0) {
#pragma unroll
    for (int j = 0; j < 3; ++j) {
      f32x4 o = *(const f32x4*)(scratch + (j*4 + dt)*256 + lane*4);
      pvacc += o;
    }
#pragma unroll
    for (int r = 0; r < 4; ++r) {
      int row = qd*4 + r;
      ao[((long)bh*N_ + n0 + row)*D_ + dt*16 + l16] = pvacc[r] / bsum[row];
    }
  }
}

// ---------------- proj GEMM (8192x320 @ 320x320^T), gathered A ----------------
__global__ __launch_bounds__(256) void proj_kernel(const float* __restrict__ ao,
    const float* __restrict__ w, const float* __restrict__ bias,
    float* __restrict__ out) {
  __shared__ float As[16][68];
  __shared__ float Bs[16][68];
  int j0 = blockIdx.x * 64;
  int m0 = blockIdx.y * 64;
  int tid = threadIdx.x;
  int tx = tid & 15, ty = tid >> 4;
  int lr = tid >> 2;
  int lc = (tid & 3) << 2;
  int m = m0 + lr;
  int bb2 = m >> 10, n = m & (N_-1);
  float acc[4][4] = {};
  for (int kk = 0; kk < C_; kk += 16) {
    int kcol = kk + lc;
    int h = kcol >> 6, dd = kcol & 63;
    float4 a4 = *(const float4*)(ao + (((long)bb2*H_ + h)*N_ + n)*D_ + dd);
    float4 b4 = *(const float4*)(w + (long)(j0+lr)*C_ + kcol);
    As[lc+0][lr]=a4.x; As[lc+1][lr]=a4.y; As[lc+2][lr]=a4.z; As[lc+3][lr]=a4.w;
    Bs[lc+0][lr]=b4.x; Bs[lc+1][lr]=b4.y; Bs[lc+2][lr]=b4.z; Bs[lc+3][lr]=b4.w;
    __syncthreads();
#pragma unroll
    for (int p = 0; p < 16; ++p) {
      float4 av = *(const float4*)&As[p][ty<<2];
      float4 bv = *(const float4*)&Bs[p][tx<<2];
      float aa[4] = {av.x,av.y,av.z,av.w};
      float bb[4] = {bv.x,bv.y,bv.z,bv.w};
#pragma unroll
      for (int i=0;i<4;++i)
#pragma unroll
        for (int j=0;j<4;++j) acc[i][j] += aa[i]*bb[j];
    }
    __syncthreads();
  }
#pragma unroll
  for (int i=0;i<4;++i) {
    int mm = m0 + (ty<<2) + i;
    float* orow = out + (long)mm*C_ + j0 + (tx<<2);
    float4 bi = *(const float4*)(bias + j0 + (tx<<2));
    float4 st = make_float4(acc[i][0]+bi.x, acc[i][1]+bi.y,
                            acc[i][2]+bi.z, acc[i][3]+bi.w);
    *(float4*)orow = st;
  }
}

extern "C" void kernel_launch(void* const* d_in, const int* in_sizes, int n_in,
                              void* d_out, int out_size, void* d_ws, size_t ws_size,
                              hipStream_t stream) {
  const float* x      = (const float*)d_in[0];
  const float* ln_g   = (const float*)d_in[1];
  const float* ln_b   = (const float*)d_in[2];
  const float* qkv_w  = (const float*)d_in[3];
  const float* qkv_b  = (const float*)d_in[4];
  const float* proj_w = (const float*)d_in[5];
  const float* proj_b = (const float*)d_in[6];
  float* out = (float*)d_out;

  char* ws = (char*)d_ws;
  const long sz_bhnd = (long)B_*H_*N_*D_;   // 2,621,440
  float*    xn   = (float*)ws;                      ws += (long)M_*C_*4;
  float*    q    = (float*)ws;                      ws += sz_bhnd*4;
  float*    k    = (float*)ws;                      ws += sz_bhnd*4;
  float*    ao   = (float*)ws;                      ws += sz_bhnd*4;
  ushort_t* vt   = (ushort_t*)ws;                   ws += sz_bhnd*2;
  ushort_t* attn = (ushort_t*)ws;                   // 40*1024*1024*2 B = 84 MB

  // Host-side 1D Gaussian kernels (separable: K = outer(u,u))
  Gauss gw;
  const float sig[H_] = {1.f, 2.f, 3.f, 4.f, 5.f};
  for (int h = 0; h < H_; ++h) {
    float g[7], s = 0.f;
    for (int t = 0; t < 7; ++t) {
      float xx = (float)(t - 3);
      g[t] = expf(-xx*xx / (2.f*sig[h]*sig[h]));
      s += g[t];
    }
    float alpha = 0.1f * (float)(h+1);
    for (int t = 0; t < 7; ++t) {
      gw.u[h][t]  = g[t] / s;
      gw.au[h][t] = alpha * g[t] / s;
    }
  }

  ln_kernel<<<M_, 64, 0, stream>>>(x, ln_g, ln_b, xn);
  qkv_kernel<<<dim3(15, 128), 256, 0, stream>>>(xn, qkv_w, qkv_b, q, k, vt);
  qk_kernel<<<dim3(16, 16, B_*H_), 256, 0, stream>>>(q, k, attn);
  bsp_kernel<<<dim3(N_/TM, B_*H_), 1024, 0, stream>>>(attn, vt, ao, gw);
  proj_kernel<<<dim3(5, 128), 256, 0, stream>>>(ao, proj_w, proj_b, out);
}